// Round 4
// baseline (112.697 us; speedup 1.0000x reference)
//
#include <hip/hip_runtime.h>
#include <math.h>

#define TT 128
#define IN_CH 32
#define NPATH 256
#define SIGCH 7380
#define K1 29520
#define N1 512
#define N2 256
#define BKK 24

// ---------------- Kernel 1: conv + time-augment + depth-4 signature ----------------
// One block per path. After staging dx into LDS, each of 243 threads owns 3
// triples (i1,i2,i3..i3+2) sharing (i1,i2) and maintains its OWN running
// S1[i1], S2[i1i2], S3[triple] scalars -> no barriers, no cross-thread deps.
__global__ __launch_bounds__(256, 1) void sig_kernel(const float* __restrict__ x,
        const float* __restrict__ cw, const float* __restrict__ cb,
        float* __restrict__ sig /*[256][7380]*/) {
    __shared__ float inc[TT][12];
    const int p = blockIdx.x;
    const int b = p >> 2, oc = p & 3;
    const int tid = threadIdx.x;

    const float4 wv = *(const float4*)(cw + oc * 4);
    const float bias = cb[oc];
    const float* xb = x + (long)b * TT * IN_CH;

    // dx staging (basepoint=True: first increment is y[0] itself)
    for (int it = tid; it < TT * 8; it += 256) {
        const int t = it >> 3, ch = it & 7;
        const float4 xa = *(const float4*)(xb + t * IN_CH + ch * 4);
        float v = xa.x * wv.x + xa.y * wv.y + xa.z * wv.z + xa.w * wv.w + bias;
        if (t > 0) {
            const float4 xm = *(const float4*)(xb + (t - 1) * IN_CH + ch * 4);
            v -= xm.x * wv.x + xm.y * wv.y + xm.z * wv.z + xm.w * wv.w + bias;
        }
        inc[t][1 + ch] = v;
    }
    for (int t = tid; t < TT; t += 256) inc[t][0] = t ? (1.f / 127.f) : 0.f;
    __syncthreads();

    if (tid >= 243) return;  // no barriers below

    const int base3 = 3 * tid;               // tr = base3 + q, q = 0..2
    const int i1 = base3 / 81;               // shared across q
    const int i2 = (base3 / 9) % 9;          // shared across q
    const int i30 = base3 % 9;               // i3 = i30 + q, stays < 9

    float S4[3][9] = {};
    float s3[3] = {0.f, 0.f, 0.f};
    float s2 = 0.f, s1 = 0.f;

    float4 A0 = *(const float4*)&inc[0][0];
    float4 A1 = *(const float4*)&inc[0][4];
    float A2 = inc[0][8];
    float e1 = inc[0][i1], e2 = inc[0][i2];
    float f0 = inc[0][i30], f1 = inc[0][i30 + 1], f2 = inc[0][i30 + 2];

#pragma unroll 2
    for (int t = 0; t < TT; ++t) {
        const int tn = (t + 1) & (TT - 1);
        const float4 nA0 = *(const float4*)&inc[tn][0];
        const float4 nA1 = *(const float4*)&inc[tn][4];
        const float nA2 = inc[tn][8];
        const float ne1 = inc[tn][i1], ne2 = inc[tn][i2];
        const float nf0 = inc[tn][i30], nf1 = inc[tn][i30 + 1], nf2 = inc[tn][i30 + 2];

        const float t12 = e1 * e2;
        const float s1d2 = s1 * e2;
        const float Ak = t12 * (1.f / 24.f) + s1d2 * (1.f / 6.f) + s2 * 0.5f;
        const float Bk = t12 * (1.f / 6.f) + s1d2 * 0.5f + s2;

        const float K0 = f0 * Ak + s3[0];
        const float K1v = f1 * Ak + s3[1];
        const float K2v = f2 * Ak + s3[2];

#define UPD(Q, KK) \
        S4[Q][0] += (KK) * A0.x; S4[Q][1] += (KK) * A0.y; \
        S4[Q][2] += (KK) * A0.z; S4[Q][3] += (KK) * A0.w; \
        S4[Q][4] += (KK) * A1.x; S4[Q][5] += (KK) * A1.y; \
        S4[Q][6] += (KK) * A1.z; S4[Q][7] += (KK) * A1.w; \
        S4[Q][8] += (KK) * A2;
        UPD(0, K0) UPD(1, K1v) UPD(2, K2v)
#undef UPD

        s3[0] += Bk * f0; s3[1] += Bk * f1; s3[2] += Bk * f2;
        s2 += e2 * (0.5f * e1 + s1);
        s1 += e1;

        A0 = nA0; A1 = nA1; A2 = nA2;
        e1 = ne1; e2 = ne2; f0 = nf0; f1 = nf1; f2 = nf2;
    }

    float* sp = sig + (long)p * SIGCH;
    if (i2 == 0 && i30 == 0) sp[i1] = s1;
    if (i30 == 0) sp[9 + base3 / 9] = s2;
    sp[90 + base3 + 0] = s3[0];
    sp[90 + base3 + 1] = s3[1];
    sp[90 + base3 + 2] = s3[2];
#pragma unroll
    for (int q = 0; q < 3; q++)
#pragma unroll
        for (int l = 0; l < 9; l++)
            sp[819 + (base3 + q) * 9 + l] = S4[q][l];
}

// ---------------- Kernel 2: GEMM1 partials ----------------
// Block = full 64x512 output tile, pure k-split grid. 256 thr, 8x16 thread
// tile: 6 ds_read_b128 per 128 FMA (LDS ratio 1.125). w tile XOR-swizzled:
// phys_slot = slot ^ ((slot>>2)&7) spreads the 64B-stride lane pattern over
// all 8 bank groups (else 4-way conflict).
__global__ __launch_bounds__(256, 1) void gemm1_kernel(const float* __restrict__ zsig,
        const float* __restrict__ w0, float* __restrict__ part, int KCH) {
    __shared__ float zT[BKK][68];    // [k][row], read as 2-addr broadcast
    __shared__ float wt[BKK][516];   // [k][swizzled cols]
    const int kc = blockIdx.x;
    const int k0 = kc * KCH;
    const int tid = threadIdx.x;
    const int ty = tid >> 5;          // 0..7  -> rows r8 = ty*8
    const int tx = tid & 31;          // 0..31 -> cols c16 = tx*16
    const int r8 = ty * 8;

    float acc[8][16] = {};

    for (int kb = 0; kb < KCH; kb += BKK) {
        const int base = k0 + kb;
        __syncthreads();
        // stage z: 64 rows x 24 k, transposed
        for (int q = tid; q < 64 * 6; q += 256) {
            const int row = q / 6, cc = (q % 6) * 4;
            float4 v = *(const float4*)(zsig + (long)row * K1 + base + cc);
            zT[cc + 0][row] = v.x; zT[cc + 1][row] = v.y;
            zT[cc + 2][row] = v.z; zT[cc + 3][row] = v.w;
        }
        // stage w: 24 rows x 512, XOR-swizzled slots
        for (int q = tid; q < BKK * 128; q += 256) {
            const int kk = q >> 7, slot = q & 127;
            float4 v = *(const float4*)(w0 + (long)(base + kk) * N1 + slot * 4);
            const int phys = slot ^ ((slot >> 2) & 7);
            *(float4*)&wt[kk][phys * 4] = v;
        }
        __syncthreads();
#pragma unroll
        for (int k = 0; k < BKK; ++k) {
            const float4 z0 = *(const float4*)&zT[k][r8];
            const float4 z1v = *(const float4*)&zT[k][r8 + 4];
            float4 wvv[4];
#pragma unroll
            for (int j = 0; j < 4; j++) {
                const int slot = tx * 4 + j;
                const int phys = slot ^ (tx & 7);
                wvv[j] = *(const float4*)&wt[k][phys * 4];
            }
            const float zr[8] = {z0.x, z0.y, z0.z, z0.w, z1v.x, z1v.y, z1v.z, z1v.w};
#pragma unroll
            for (int r = 0; r < 8; r++) {
#pragma unroll
                for (int j = 0; j < 4; j++) {
                    acc[r][j * 4 + 0] += zr[r] * wvv[j].x;
                    acc[r][j * 4 + 1] += zr[r] * wvv[j].y;
                    acc[r][j * 4 + 2] += zr[r] * wvv[j].z;
                    acc[r][j * 4 + 3] += zr[r] * wvv[j].w;
                }
            }
        }
    }
    // write partial tile: part[kc][64][512]
    float* pp = part + ((long)kc * 64 + r8) * N1 + tx * 16;
#pragma unroll
    for (int r = 0; r < 8; r++)
#pragma unroll
        for (int j = 0; j < 4; j++)
            *(float4*)(pp + (long)r * N1 + j * 4) =
                make_float4(acc[r][j * 4 + 0], acc[r][j * 4 + 1],
                            acc[r][j * 4 + 2], acc[r][j * 4 + 3]);
}

// ---------------- Kernel 3: reduce partials + bias + sigmoid ----------------
__global__ __launch_bounds__(256) void red1_kernel(const float* __restrict__ part,
        const float* __restrict__ b0v, float* __restrict__ z1, int ksplit) {
    __shared__ float4 red[256];
    const int tid = threadIdx.x;
    const int g = tid & 31, s = tid >> 5;
    const int gg = blockIdx.x * 32 + g;           // float4 index in [0, 8192)
    const int per = (ksplit + 7) >> 3;
    const int ks = s * per, ke = min(ksplit, ks + per);
    float4 a = make_float4(0.f, 0.f, 0.f, 0.f);
    for (int kc = ks; kc < ke; kc++) {
        float4 pv = *(const float4*)(part + ((long)kc * 8192 + gg) * 4);
        a.x += pv.x; a.y += pv.y; a.z += pv.z; a.w += pv.w;
    }
    red[tid] = a;
    __syncthreads();
    if (tid < 128) { float4 o = red[tid + 128]; red[tid].x += o.x; red[tid].y += o.y; red[tid].z += o.z; red[tid].w += o.w; }
    __syncthreads();
    if (tid < 64) { float4 o = red[tid + 64]; red[tid].x += o.x; red[tid].y += o.y; red[tid].z += o.z; red[tid].w += o.w; }
    __syncthreads();
    if (tid < 32) {
        float4 sum = red[tid];
        float4 o = red[tid + 32];
        sum.x += o.x; sum.y += o.y; sum.z += o.z; sum.w += o.w;
        const float4 bv = *(const float4*)(b0v + (gg & 127) * 4);
        float4 r;
        r.x = 1.f / (1.f + expf(-(sum.x + bv.x)));
        r.y = 1.f / (1.f + expf(-(sum.y + bv.y)));
        r.z = 1.f / (1.f + expf(-(sum.z + bv.z)));
        r.w = 1.f / (1.f + expf(-(sum.w + bv.w)));
        *(float4*)(z1 + gg * 4) = r;
    }
}

// ---------------- Kernel 4: GEMM2 + bias + sigmoid (in-block K-split) ----------------
__global__ __launch_bounds__(256) void gemm2_kernel(const float* __restrict__ z1,
        const float* __restrict__ w1, const float* __restrict__ b1v,
        float* __restrict__ z2) {
    __shared__ float red[256];
    const int m = blockIdx.x >> 2, nq = blockIdx.x & 3;
    const int tid = threadIdx.x;
    const int c = tid & 63, s = tid >> 6;
    const int n = nq * 64 + c;
    const float* zr = z1 + m * N1 + s * 128;
    const float* wr = w1 + (long)(s * 128) * N2 + n;
    float acc = 0.f;
#pragma unroll 16
    for (int k = 0; k < 128; k++) acc += zr[k] * wr[(long)k * N2];
    red[tid] = acc;
    __syncthreads();
    if (tid < 128) red[tid] += red[tid + 128];
    __syncthreads();
    if (tid < 64) {
        float sum = red[tid] + red[tid + 64] + b1v[n];
        z2[m * N2 + n] = 1.f / (1.f + expf(-sum));
    }
}

// ---------------- Kernel 5: GEMM3 + log_softmax ----------------
__global__ __launch_bounds__(64) void head_kernel(const float* __restrict__ z2,
        const float* __restrict__ w2, const float* __restrict__ b2v,
        float* __restrict__ out) {
    const int m = blockIdx.x;
    const int tid = threadIdx.x;
    __shared__ float logits[10];
    if (tid < 10) {
        float s = b2v[tid];
        const float* zr = z2 + m * N2;
#pragma unroll 8
        for (int k = 0; k < N2; k++) s += zr[k] * w2[k * 10 + tid];
        logits[tid] = s;
    }
    __syncthreads();
    if (tid == 0) {
        float mx = logits[0];
        for (int j = 1; j < 10; j++) mx = fmaxf(mx, logits[j]);
        float sum = 0.f;
        for (int j = 0; j < 10; j++) sum += expf(logits[j] - mx);
        const float lse = mx + logf(sum);
        for (int j = 0; j < 10; j++) out[m * 10 + j] = logits[j] - lse;
    }
}

extern "C" void kernel_launch(void* const* d_in, const int* in_sizes, int n_in,
                              void* d_out, int out_size, void* d_ws, size_t ws_size,
                              hipStream_t stream) {
    const float* x  = (const float*)d_in[0];
    const float* cw = (const float*)d_in[1];
    const float* cb = (const float*)d_in[2];
    const float* w0 = (const float*)d_in[3];
    const float* b0 = (const float*)d_in[4];
    const float* w1 = (const float*)d_in[5];
    const float* b1 = (const float*)d_in[6];
    const float* w2 = (const float*)d_in[7];
    const float* b2 = (const float*)d_in[8];

    // tiered K-split by workspace: 29520 = ksplit * KCH, KCH % 24 == 0
    const size_t fixed = (size_t)NPATH * SIGCH + 64 * N1 + 64 * N2;
    int ksplit = 82, kch = 360;
    if (ws_size >= (fixed + (size_t)246 * 64 * N1) * 4)      { ksplit = 246; kch = 120; }
    else if (ws_size >= (fixed + (size_t)205 * 64 * N1) * 4) { ksplit = 205; kch = 144; }
    else if (ws_size >= (fixed + (size_t)123 * 64 * N1) * 4) { ksplit = 123; kch = 240; }

    float* ws   = (float*)d_ws;
    float* sig  = ws;                                // 256*7380
    float* part = sig + (long)NPATH * SIGCH;         // ksplit*64*512
    float* z1   = part + (long)ksplit * 64 * N1;     // 64*512
    float* z2   = z1 + 64 * N1;                      // 64*256
    float* out  = (float*)d_out;

    sig_kernel<<<NPATH, 256, 0, stream>>>(x, cw, cb, sig);
    gemm1_kernel<<<ksplit, 256, 0, stream>>>(sig, w0, part, kch);
    red1_kernel<<<256, 256, 0, stream>>>(part, b0, z1, ksplit);
    gemm2_kernel<<<256, 256, 0, stream>>>(z1, w1, b1, z2);
    head_kernel<<<64, 64, 0, stream>>>(z2, w2, b2, out);
}

// Round 5
// 92.634 us; speedup vs baseline: 1.2166x; 1.2166x over previous
//
#include <hip/hip_runtime.h>
#include <math.h>

#define TT 128
#define IN_CH 32
#define NPATH 256
#define SIGCH 7380
#define K1 29520
#define N1 512
#define N2 256
#define BKK 24

// ---------------- Kernel 1: conv + time-augment + depth-4 signature ----------------
// One block per path. After staging dx into LDS, each of 243 threads owns 3
// triples (i1,i2,i3..i3+2) sharing (i1,i2) and maintains its OWN running
// S1[i1], S2[i1i2], S3[triple] scalars -> no barriers, no cross-thread deps.
__global__ __launch_bounds__(256, 1) void sig_kernel(const float* __restrict__ x,
        const float* __restrict__ cw, const float* __restrict__ cb,
        float* __restrict__ sig /*[256][7380]*/) {
    __shared__ float inc[TT][12];
    const int p = blockIdx.x;
    const int b = p >> 2, oc = p & 3;
    const int tid = threadIdx.x;

    const float4 wv = *(const float4*)(cw + oc * 4);
    const float bias = cb[oc];
    const float* xb = x + (long)b * TT * IN_CH;

    // dx staging (basepoint=True: first increment is y[0] itself)
    for (int it = tid; it < TT * 8; it += 256) {
        const int t = it >> 3, ch = it & 7;
        const float4 xa = *(const float4*)(xb + t * IN_CH + ch * 4);
        float v = xa.x * wv.x + xa.y * wv.y + xa.z * wv.z + xa.w * wv.w + bias;
        if (t > 0) {
            const float4 xm = *(const float4*)(xb + (t - 1) * IN_CH + ch * 4);
            v -= xm.x * wv.x + xm.y * wv.y + xm.z * wv.z + xm.w * wv.w + bias;
        }
        inc[t][1 + ch] = v;
    }
    for (int t = tid; t < TT; t += 256) inc[t][0] = t ? (1.f / 127.f) : 0.f;
    __syncthreads();

    if (tid >= 243) return;  // no barriers below

    const int base3 = 3 * tid;               // tr = base3 + q, q = 0..2
    const int i1 = base3 / 81;               // shared across q
    const int i2 = (base3 / 9) % 9;          // shared across q
    const int i30 = base3 % 9;               // i3 = i30 + q, stays < 9

    float S4[3][9] = {};
    float s3[3] = {0.f, 0.f, 0.f};
    float s2 = 0.f, s1 = 0.f;

    float4 A0 = *(const float4*)&inc[0][0];
    float4 A1 = *(const float4*)&inc[0][4];
    float A2 = inc[0][8];
    float e1 = inc[0][i1], e2 = inc[0][i2];
    float f0 = inc[0][i30], f1 = inc[0][i30 + 1], f2 = inc[0][i30 + 2];

#pragma unroll 2
    for (int t = 0; t < TT; ++t) {
        const int tn = (t + 1) & (TT - 1);
        const float4 nA0 = *(const float4*)&inc[tn][0];
        const float4 nA1 = *(const float4*)&inc[tn][4];
        const float nA2 = inc[tn][8];
        const float ne1 = inc[tn][i1], ne2 = inc[tn][i2];
        const float nf0 = inc[tn][i30], nf1 = inc[tn][i30 + 1], nf2 = inc[tn][i30 + 2];

        const float t12 = e1 * e2;
        const float s1d2 = s1 * e2;
        const float Ak = t12 * (1.f / 24.f) + s1d2 * (1.f / 6.f) + s2 * 0.5f;
        const float Bk = t12 * (1.f / 6.f) + s1d2 * 0.5f + s2;

        const float K0 = f0 * Ak + s3[0];
        const float K1v = f1 * Ak + s3[1];
        const float K2v = f2 * Ak + s3[2];

#define UPD(Q, KK) \
        S4[Q][0] += (KK) * A0.x; S4[Q][1] += (KK) * A0.y; \
        S4[Q][2] += (KK) * A0.z; S4[Q][3] += (KK) * A0.w; \
        S4[Q][4] += (KK) * A1.x; S4[Q][5] += (KK) * A1.y; \
        S4[Q][6] += (KK) * A1.z; S4[Q][7] += (KK) * A1.w; \
        S4[Q][8] += (KK) * A2;
        UPD(0, K0) UPD(1, K1v) UPD(2, K2v)
#undef UPD

        s3[0] += Bk * f0; s3[1] += Bk * f1; s3[2] += Bk * f2;
        s2 += e2 * (0.5f * e1 + s1);
        s1 += e1;

        A0 = nA0; A1 = nA1; A2 = nA2;
        e1 = ne1; e2 = ne2; f0 = nf0; f1 = nf1; f2 = nf2;
    }

    float* sp = sig + (long)p * SIGCH;
    if (i2 == 0 && i30 == 0) sp[i1] = s1;
    if (i30 == 0) sp[9 + base3 / 9] = s2;
    sp[90 + base3 + 0] = s3[0];
    sp[90 + base3 + 1] = s3[1];
    sp[90 + base3 + 2] = s3[2];
#pragma unroll
    for (int q = 0; q < 3; q++)
#pragma unroll
        for (int l = 0; l < 9; l++)
            sp[819 + (base3 + q) * 9 + l] = S4[q][l];
}

// ---------------- Kernel 2: GEMM1 partials ----------------
// 64x128 block tile, 8x4 thread tile, grid = 4 n-tiles x ksplit.
// Per k-step: 2 broadcast ds_read_b128 (zT) + 1 contiguous ds_read_b128 (wt,
// conflict-free: 32 lanes read 32 consecutive float4s = all 32 banks x4 words)
// per 32 FMA/thread -> LDS ratio ~1.0, ~4 blocks/CU.
__global__ __launch_bounds__(256) void gemm1_kernel(const float* __restrict__ zsig,
        const float* __restrict__ w0, float* __restrict__ part, int KCH) {
    __shared__ float zT[BKK][68];    // [k][row], broadcast reads
    __shared__ float wt[BKK][132];   // [k][col], contiguous reads
    const int nq = blockIdx.x;       // 0..3
    const int kc = blockIdx.y;
    const int n0 = nq * 128, k0 = kc * KCH;
    const int tid = threadIdx.x;
    const int tx = tid & 31, ty = tid >> 5;
    const int r8 = ty * 8, c4 = tx * 4;

    float acc[8][4] = {};

    for (int kb = 0; kb < KCH; kb += BKK) {
        const int base = k0 + kb;
        __syncthreads();
        // stage z: 64 rows x 24 k, transposed (384 float4)
        for (int q = tid; q < 384; q += 256) {
            const int row = q / 6, cc = (q % 6) * 4;
            float4 v = *(const float4*)(zsig + (long)row * K1 + base + cc);
            zT[cc + 0][row] = v.x; zT[cc + 1][row] = v.y;
            zT[cc + 2][row] = v.z; zT[cc + 3][row] = v.w;
        }
        // stage w: 24 k x 128 cols (768 float4), coalesced, linear
        for (int q = tid; q < 768; q += 256) {
            const int kk = q >> 5, s = q & 31;
            *(float4*)&wt[kk][s * 4] =
                *(const float4*)(w0 + (long)(base + kk) * N1 + n0 + s * 4);
        }
        __syncthreads();
#pragma unroll
        for (int k = 0; k < BKK; ++k) {
            const float4 z0 = *(const float4*)&zT[k][r8];
            const float4 z1v = *(const float4*)&zT[k][r8 + 4];
            const float4 wf = *(const float4*)&wt[k][c4];
            acc[0][0] += z0.x * wf.x; acc[0][1] += z0.x * wf.y; acc[0][2] += z0.x * wf.z; acc[0][3] += z0.x * wf.w;
            acc[1][0] += z0.y * wf.x; acc[1][1] += z0.y * wf.y; acc[1][2] += z0.y * wf.z; acc[1][3] += z0.y * wf.w;
            acc[2][0] += z0.z * wf.x; acc[2][1] += z0.z * wf.y; acc[2][2] += z0.z * wf.z; acc[2][3] += z0.z * wf.w;
            acc[3][0] += z0.w * wf.x; acc[3][1] += z0.w * wf.y; acc[3][2] += z0.w * wf.z; acc[3][3] += z0.w * wf.w;
            acc[4][0] += z1v.x * wf.x; acc[4][1] += z1v.x * wf.y; acc[4][2] += z1v.x * wf.z; acc[4][3] += z1v.x * wf.w;
            acc[5][0] += z1v.y * wf.x; acc[5][1] += z1v.y * wf.y; acc[5][2] += z1v.y * wf.z; acc[5][3] += z1v.y * wf.w;
            acc[6][0] += z1v.z * wf.x; acc[6][1] += z1v.z * wf.y; acc[6][2] += z1v.z * wf.z; acc[6][3] += z1v.z * wf.w;
            acc[7][0] += z1v.w * wf.x; acc[7][1] += z1v.w * wf.y; acc[7][2] += z1v.w * wf.z; acc[7][3] += z1v.w * wf.w;
        }
    }
    // write partial tile: part[kc][64][512]
    float* pp = part + ((long)kc * 64 + r8) * N1 + n0 + c4;
#pragma unroll
    for (int r = 0; r < 8; r++)
        *(float4*)(pp + (long)r * N1) =
            make_float4(acc[r][0], acc[r][1], acc[r][2], acc[r][3]);
}

// ---------------- Kernel 3: reduce partials + bias + sigmoid ----------------
__global__ __launch_bounds__(256) void red1_kernel(const float* __restrict__ part,
        const float* __restrict__ b0v, float* __restrict__ z1, int ksplit) {
    __shared__ float4 red[256];
    const int tid = threadIdx.x;
    const int g = tid & 31, s = tid >> 5;
    const int gg = blockIdx.x * 32 + g;           // float4 index in [0, 8192)
    const int per = (ksplit + 7) >> 3;
    const int ks = s * per, ke = min(ksplit, ks + per);
    float4 a = make_float4(0.f, 0.f, 0.f, 0.f);
    for (int kc = ks; kc < ke; kc++) {
        float4 pv = *(const float4*)(part + ((long)kc * 8192 + gg) * 4);
        a.x += pv.x; a.y += pv.y; a.z += pv.z; a.w += pv.w;
    }
    red[tid] = a;
    __syncthreads();
    if (tid < 128) { float4 o = red[tid + 128]; red[tid].x += o.x; red[tid].y += o.y; red[tid].z += o.z; red[tid].w += o.w; }
    __syncthreads();
    if (tid < 64) { float4 o = red[tid + 64]; red[tid].x += o.x; red[tid].y += o.y; red[tid].z += o.z; red[tid].w += o.w; }
    __syncthreads();
    if (tid < 32) {
        float4 sum = red[tid];
        float4 o = red[tid + 32];
        sum.x += o.x; sum.y += o.y; sum.z += o.z; sum.w += o.w;
        const float4 bv = *(const float4*)(b0v + (gg & 127) * 4);
        float4 r;
        r.x = 1.f / (1.f + expf(-(sum.x + bv.x)));
        r.y = 1.f / (1.f + expf(-(sum.y + bv.y)));
        r.z = 1.f / (1.f + expf(-(sum.z + bv.z)));
        r.w = 1.f / (1.f + expf(-(sum.w + bv.w)));
        *(float4*)(z1 + gg * 4) = r;
    }
}

// ---------------- Kernel 4: GEMM2 + bias + sigmoid (in-block K-split) ----------------
__global__ __launch_bounds__(256) void gemm2_kernel(const float* __restrict__ z1,
        const float* __restrict__ w1, const float* __restrict__ b1v,
        float* __restrict__ z2) {
    __shared__ float red[256];
    const int m = blockIdx.x >> 2, nq = blockIdx.x & 3;
    const int tid = threadIdx.x;
    const int c = tid & 63, s = tid >> 6;
    const int n = nq * 64 + c;
    const float* zr = z1 + m * N1 + s * 128;
    const float* wr = w1 + (long)(s * 128) * N2 + n;
    float acc = 0.f;
#pragma unroll 16
    for (int k = 0; k < 128; k++) acc += zr[k] * wr[(long)k * N2];
    red[tid] = acc;
    __syncthreads();
    if (tid < 128) red[tid] += red[tid + 128];
    __syncthreads();
    if (tid < 64) {
        float sum = red[tid] + red[tid + 64] + b1v[n];
        z2[m * N2 + n] = 1.f / (1.f + expf(-sum));
    }
}

// ---------------- Kernel 5: GEMM3 + log_softmax ----------------
__global__ __launch_bounds__(64) void head_kernel(const float* __restrict__ z2,
        const float* __restrict__ w2, const float* __restrict__ b2v,
        float* __restrict__ out) {
    const int m = blockIdx.x;
    const int tid = threadIdx.x;
    __shared__ float logits[10];
    if (tid < 10) {
        float s = b2v[tid];
        const float* zr = z2 + m * N2;
#pragma unroll 8
        for (int k = 0; k < N2; k++) s += zr[k] * w2[k * 10 + tid];
        logits[tid] = s;
    }
    __syncthreads();
    if (tid == 0) {
        float mx = logits[0];
        for (int j = 1; j < 10; j++) mx = fmaxf(mx, logits[j]);
        float sum = 0.f;
        for (int j = 0; j < 10; j++) sum += expf(logits[j] - mx);
        const float lse = mx + logf(sum);
        for (int j = 0; j < 10; j++) out[m * 10 + j] = logits[j] - lse;
    }
}

extern "C" void kernel_launch(void* const* d_in, const int* in_sizes, int n_in,
                              void* d_out, int out_size, void* d_ws, size_t ws_size,
                              hipStream_t stream) {
    const float* x  = (const float*)d_in[0];
    const float* cw = (const float*)d_in[1];
    const float* cb = (const float*)d_in[2];
    const float* w0 = (const float*)d_in[3];
    const float* b0 = (const float*)d_in[4];
    const float* w1 = (const float*)d_in[5];
    const float* b1 = (const float*)d_in[6];
    const float* w2 = (const float*)d_in[7];
    const float* b2 = (const float*)d_in[8];

    // tiered K-split by workspace: 29520 = ksplit * KCH, KCH % 24 == 0
    const size_t fixed = (size_t)NPATH * SIGCH + 64 * N1 + 64 * N2;
    int ksplit = 82, kch = 360;
    if (ws_size >= (fixed + (size_t)246 * 64 * N1) * 4)      { ksplit = 246; kch = 120; }
    else if (ws_size >= (fixed + (size_t)123 * 64 * N1) * 4) { ksplit = 123; kch = 240; }

    float* ws   = (float*)d_ws;
    float* sig  = ws;                                // 256*7380
    float* part = sig + (long)NPATH * SIGCH;         // ksplit*64*512
    float* z1   = part + (long)ksplit * 64 * N1;     // 64*512
    float* z2   = z1 + 64 * N1;                      // 64*256
    float* out  = (float*)d_out;

    sig_kernel<<<NPATH, 256, 0, stream>>>(x, cw, cb, sig);
    gemm1_kernel<<<dim3(4, ksplit), 256, 0, stream>>>(sig, w0, part, kch);
    red1_kernel<<<256, 256, 0, stream>>>(part, b0, z1, ksplit);
    gemm2_kernel<<<256, 256, 0, stream>>>(z1, w1, b1, z2);
    head_kernel<<<64, 64, 0, stream>>>(z2, w2, b2, out);
}